// Round 7
// baseline (256.688 us; speedup 1.0000x reference)
//
#include <hip/hip_runtime.h>
#include <hip/hip_bf16.h>

#define B_  32
#define C_  1024
#define N_  256
#define DQ_ 64

typedef __bf16 bf16_t;
typedef __bf16 bf16x8 __attribute__((ext_vector_type(8)));
typedef float  f32x4  __attribute__((ext_vector_type(4)));

static __device__ __forceinline__ f32x4 mfma16(bf16x8 a, bf16x8 b, f32x4 c) {
  return __builtin_amdgcn_mfma_f32_16x16x32_bf16(a, b, c, 0, 0, 0);
}

static __device__ __forceinline__ bf16x8 ldcvt(const float* p) {
  const float4 a = *(const float4*)p;
  const float4 b = *(const float4*)(p + 4);
  bf16x8 r;
  r[0] = (bf16_t)a.x; r[1] = (bf16_t)a.y; r[2] = (bf16_t)a.z; r[3] = (bf16_t)a.w;
  r[4] = (bf16_t)b.x; r[5] = (bf16_t)b.y; r[6] = (bf16_t)b.z; r[7] = (bf16_t)b.w;
  return r;
}

// wait until at most N VMEM ops outstanding (exp/lgkm unconstrained)
#define WAIT_VMCNT(N) __builtin_amdgcn_s_waitcnt(0x0F70 | (N))

// ---------------- Kernel T: x (B,C,N) f32 -> xT (B,N,C) bf16 ----------------
__global__ __launch_bounds__(256) void k_trans(const float* __restrict__ x,
                                               bf16_t* __restrict__ xT) {
  __shared__ bf16_t tile[32][34];
  const int b  = blockIdx.z;
  const int n0 = blockIdx.x * 32, c0 = blockIdx.y * 32;
  const int tx = threadIdx.x, ty = threadIdx.y;
  const float* xb = x + (size_t)b * C_ * N_;
  bf16_t*     xtb = xT + (size_t)b * N_ * C_;
#pragma unroll
  for (int i = 0; i < 4; ++i)
    tile[ty + i * 8][tx] = (bf16_t)xb[(size_t)(c0 + ty + i * 8) * N_ + (n0 + tx)];
  __syncthreads();
#pragma unroll
  for (int i = 0; i < 4; ++i)
    xtb[(size_t)(n0 + ty + i * 8) * C_ + (c0 + tx)] = tile[tx][ty + i * 8];
}

// ---------------- Kernel CVT: Wv, Wq, Wk f32 -> bf16 ----------------
__global__ __launch_bounds__(256) void k_cvt(const float* __restrict__ Wv,
                                             const float* __restrict__ Wq,
                                             const float* __restrict__ Wk,
                                             bf16_t* __restrict__ Wvb,
                                             bf16_t* __restrict__ Wqkb) {
  const int gid = blockIdx.x * 256 + threadIdx.x;
  if (blockIdx.x < 512) {
    const int i = gid * 8;
    *(bf16x8*)(Wvb + i) = ldcvt(Wv + i);
  } else {
    const int g2 = (gid - 512 * 256) * 8;
    if (g2 < 16384) *(bf16x8*)(Wqkb + g2) = ldcvt(Wq + g2);
    else            *(bf16x8*)(Wqkb + g2) = ldcvt(Wk + (g2 - 16384));
  }
}

// ---------------- Kernel 1: fused q+k projection, W staged in LDS ----------------
__global__ __launch_bounds__(256) void k_qk(const float* __restrict__ x,
                                            const bf16_t* __restrict__ Wqkb,
                                            const float* __restrict__ g1,
                                            const float* __restrict__ b1,
                                            const float* __restrict__ m1,
                                            const float* __restrict__ v1,
                                            const float* __restrict__ g2,
                                            const float* __restrict__ b2,
                                            const float* __restrict__ m2,
                                            const float* __restrict__ v2,
                                            bf16_t* __restrict__ qt,
                                            bf16_t* __restrict__ kt) {
  __shared__ __align__(16) bf16_t Ws[128 * 256];
  const int tid  = threadIdx.x;
  const int wave = tid >> 6;
  const int lane = tid & 63;
  const int quad = lane >> 4;
  const int l16  = lane & 15;
  const int b    = blockIdx.y;
  const int c16  = blockIdx.x * 64 + wave * 16;
  const float* xb = x + (size_t)b * C_ * N_;

  // stage Wqkb -> Ws (rotated: row o, chunk ch at slot (ch+o)&31)
#pragma unroll
  for (int t = 0; t < 16; ++t) {
    const int o = wave * 32 + t * 2 + (lane >> 5);
    const int s = lane & 31;
    const int g = (s - o) & 31;
    const bf16_t* src = Wqkb + (size_t)o * N_ + g * 8;
    __builtin_amdgcn_global_load_lds(
        (const __attribute__((address_space(1))) void*)src,
        (__attribute__((address_space(3))) void*)(Ws + (wave * 32 + t * 2) * N_ + lane * 8),
        16, 0, 0);
  }

  bf16x8 bx[8];
#pragma unroll
  for (int ks = 0; ks < 8; ++ks)
    bx[ks] = ldcvt(xb + (size_t)(c16 + l16) * N_ + ks * 32 + quad * 8);

  __syncthreads();   // drains DMA (compiler emits vmcnt(0) before s_barrier)

  f32x4 acc[8];
#pragma unroll
  for (int i = 0; i < 8; ++i) acc[i] = (f32x4){0.f, 0.f, 0.f, 0.f};

#pragma unroll
  for (int ks = 0; ks < 8; ++ks) {
    const int ch = ks * 4 + quad;
#pragma unroll
    for (int i = 0; i < 8; ++i) {
      const int orow = i * 16 + l16;
      const int s = (ch + orow) & 31;
      const bf16x8 aw = *(const bf16x8*)(Ws + (size_t)orow * N_ + s * 8);
      acc[i] = mfma16(aw, bx[ks], acc[i]);
    }
  }

#pragma unroll
  for (int i = 0; i < 8; ++i) {
    const bool isq = (i < 4);
    bf16_t* dst = isq ? qt : kt;
#pragma unroll
    for (int r = 0; r < 4; ++r) {
      const int o = (i & 3) * 16 + quad * 4 + r;
      const float sc = (isq ? g1[o] : g2[o]) * rsqrtf((isq ? v1[o] : v2[o]) + 1e-5f);
      const float mm = isq ? m1[o] : m2[o];
      const float bt = isq ? b1[o] : b2[o];
      const int c = c16 + l16;
      float y = (acc[i][r] - mm) * sc + bt;
      y = fmaxf(y, 0.f);
      dst[((size_t)b * C_ + c) * DQ_ + o] = (bf16_t)y;
    }
  }
}

// Swizzled block-wide staging (k_vgemm): wave stages 32 rows x 64 bf16.
static __device__ __forceinline__ void stage32(const bf16_t* grow0, size_t gstride,
                                               bf16_t* tile, int wave, int lane) {
#pragma unroll
  for (int t = 0; t < 4; ++t) {
    const int rb = wave * 32 + t * 8;
    const int r  = rb + (lane >> 3);
    const int g  = ((lane & 7) - r) & 7;
    const bf16_t* src = grow0 + (size_t)r * gstride + g * 8;
    __builtin_amdgcn_global_load_lds(
        (const __attribute__((address_space(1))) void*)src,
        (__attribute__((address_space(3))) void*)(tile + rb * 64), 16, 0, 0);
  }
}

// ---------------- Kernel 2: v GEMM, m97-style staged (flat 8192x1024x1024) ----
__global__ __launch_bounds__(256, 2) void k_vgemm(const bf16_t* __restrict__ Wvb,
                                                  const bf16_t* __restrict__ xT,
                                                  const float* __restrict__ g,
                                                  const float* __restrict__ be,
                                                  const float* __restrict__ mu,
                                                  const float* __restrict__ va,
                                                  bf16_t* __restrict__ vT) {
  __shared__ __align__(16) bf16_t As[2][128 * 64];
  __shared__ __align__(16) bf16_t Bs[2][128 * 64];
  const int tid  = threadIdx.x;
  const int wave = tid >> 6;
  const int lane = tid & 63;
  const int quad = lane >> 4;
  const int l16  = lane & 15;
  const int o0 = blockIdx.x * 128;
  const int r0 = blockIdx.y * 128;
  const bf16_t* Ab = Wvb + (size_t)o0 * C_;
  const bf16_t* Bb = xT + (size_t)r0 * C_;
  const int wr = (wave >> 1) * 64, wc = (wave & 1) * 64;

  stage32(Ab, C_, (bf16_t*)As[0], wave, lane);
  stage32(Bb, C_, (bf16_t*)Bs[0], wave, lane);

  f32x4 acc[4][4];
#pragma unroll
  for (int i = 0; i < 4; ++i)
#pragma unroll
    for (int j = 0; j < 4; ++j) acc[i][j] = (f32x4){0.f, 0.f, 0.f, 0.f};

  for (int ks = 0; ks < 16; ++ks) {
    __syncthreads();
    const bf16_t* ca = As[ks & 1];
    const bf16_t* cb = Bs[ks & 1];
    if (ks < 15) {
      stage32(Ab + (ks + 1) * 64, C_, (bf16_t*)As[(ks + 1) & 1], wave, lane);
      stage32(Bb + (ks + 1) * 64, C_, (bf16_t*)Bs[(ks + 1) & 1], wave, lane);
    }
#pragma unroll
    for (int ksub = 0; ksub < 2; ++ksub) {
      bf16x8 a[4], bfr[4];
#pragma unroll
      for (int i = 0; i < 4; ++i) {
        const int r = wr + i * 16 + l16;
        const int s = ((ksub * 4 + quad) + r) & 7;
        a[i] = *(const bf16x8*)(ca + r * 64 + s * 8);
      }
#pragma unroll
      for (int j = 0; j < 4; ++j) {
        const int r = wc + j * 16 + l16;
        const int s = ((ksub * 4 + quad) + r) & 7;
        bfr[j] = *(const bf16x8*)(cb + r * 64 + s * 8);
      }
#pragma unroll
      for (int i = 0; i < 4; ++i)
#pragma unroll
        for (int j = 0; j < 4; ++j)
          acc[i][j] = mfma16(a[i], bfr[j], acc[i][j]);
    }
  }

#pragma unroll
  for (int i = 0; i < 4; ++i)
#pragma unroll
    for (int r = 0; r < 4; ++r) {
      const int o = o0 + wr + i * 16 + quad * 4 + r;
      const float sc = g[o] * rsqrtf(va[o] + 1e-5f);
      const float mm = mu[o], bt = be[o];
#pragma unroll
      for (int j = 0; j < 4; ++j) {
        const int rG = r0 + wc + j * 16 + l16;
        float y = (acc[i][j][r] - mm) * sc + bt;
        y = fmaxf(y, 0.f);
        vT[(size_t)rG * C_ + o] = (bf16_t)y;
      }
    }
}

// ---------------- Kernel 3: fused sim -> softmax -> out ----------------
// 256 thr / 4 waves. 16 c-rows/block. Phase C: barrier-free wave-private
// double-buffered DMA pipeline with EXPLICIT vmcnt waits.
static __device__ __forceinline__ int eaddr16(int c, int d) {
  const int ch = d >> 3;
  const int ph = (ch & ~7) | ((ch + c) & 7);
  return (c << 10) + (ph << 3) + (d & 7);
}

__global__ __launch_bounds__(256, 2) void k_fused(const bf16_t* __restrict__ qt,
                                                  const bf16_t* __restrict__ kt,
                                                  const bf16_t* __restrict__ vT,
                                                  const float* __restrict__ x,
                                                  const float* __restrict__ alphap,
                                                  float* __restrict__ out) {
  __shared__ __align__(16) bf16_t ebuf[16 * 1024];     // rotated, 32 KB
  __shared__ __align__(16) bf16_t vs[2][4][64 * 32];   // per-wave dbuf, 32 KB
  __shared__ float redmin[4][16];
  __shared__ float redsum[4][16];
  __shared__ float rowmin[16];
  __shared__ float rowrinv[16];

  const int tid  = threadIdx.x;
  const int wave = tid >> 6;
  const int lane = tid & 63;
  const int quad = lane >> 4;
  const int l16  = lane & 15;
  const int id   = blockIdx.x;
  const int b    = ((id & 7) << 2) | (id >> 9);     // 64 blocks/batch, one XCD each
  const int c0   = ((id >> 3) & 63) << 4;
  const int dbase = wave * 256;

  // ---- Phase A: sim (16 c x 1024 d), qt direct from L2 ----
  const bf16_t* ktb = kt + ((size_t)b * C_ + c0) * DQ_;
  const bf16_t* qb  = qt + (size_t)b * C_ * DQ_;
  bf16x8 am[2];
  am[0] = *(const bf16x8*)(ktb + (size_t)l16 * DQ_ + quad * 8);
  am[1] = *(const bf16x8*)(ktb + (size_t)l16 * DQ_ + 32 + quad * 8);
  f32x4 sim[16];
#pragma unroll
  for (int nt = 0; nt < 16; ++nt) {
    const bf16_t* qrow = qb + (size_t)(dbase + nt * 16 + l16) * DQ_ + quad * 8;
    const bf16x8 b0 = *(const bf16x8*)(qrow);
    const bf16x8 b1 = *(const bf16x8*)(qrow + 32);
    f32x4 acc = (f32x4){0.f, 0.f, 0.f, 0.f};
    acc = mfma16(am[0], b0, acc);
    acc = mfma16(am[1], b1, acc);
    sim[nt] = acc;
  }

  // ---- Prologue for Phase C: stage k-tile 0 now; Phase B hides the latency,
  //      and Phase B's barriers drain it (vmcnt(0) before s_barrier). ----
  const bf16_t* vb = vT + ((size_t)b * N_ + wave * 64) * C_;
  bf16_t* myvs[2] = {(bf16_t*)vs[0][wave], (bf16_t*)vs[1][wave]};
#pragma unroll
  for (int t = 0; t < 4; ++t) {
    const int r = t * 16 + (lane >> 2);
    const int gg = ((lane & 3) - (r + (r >> 2))) & 3;
    const bf16_t* src = vb + (size_t)r * C_ + gg * 8;
    __builtin_amdgcn_global_load_lds(
        (const __attribute__((address_space(1))) void*)src,
        (__attribute__((address_space(3))) void*)(myvs[0] + t * 512 + lane * 8),
        16, 0, 0);
  }

  // ---- Phase B: row-min shift, exp, row-sum ----
  float pmin[4];
#pragma unroll
  for (int r = 0; r < 4; ++r) pmin[r] = sim[0][r];
#pragma unroll
  for (int nt = 1; nt < 16; ++nt)
#pragma unroll
    for (int r = 0; r < 4; ++r) pmin[r] = fminf(pmin[r], sim[nt][r]);
#pragma unroll
  for (int m = 1; m < 16; m <<= 1)
#pragma unroll
    for (int r = 0; r < 4; ++r) pmin[r] = fminf(pmin[r], __shfl_xor(pmin[r], m));
  if (l16 == 0)
#pragma unroll
    for (int r = 0; r < 4; ++r) redmin[wave][quad * 4 + r] = pmin[r];
  __syncthreads();
  if (tid < 16)
    rowmin[tid] = fminf(fminf(redmin[0][tid], redmin[1][tid]),
                        fminf(redmin[2][tid], redmin[3][tid]));
  __syncthreads();

  float mn[4], psum[4] = {0.f, 0.f, 0.f, 0.f};
#pragma unroll
  for (int r = 0; r < 4; ++r) mn[r] = rowmin[quad * 4 + r];
#pragma unroll
  for (int nt = 0; nt < 16; ++nt) {
    const int d = dbase + nt * 16 + l16;
#pragma unroll
    for (int r = 0; r < 4; ++r) {
      const int c = quad * 4 + r;
      const float e = __expf(mn[r] - sim[nt][r]);
      ebuf[eaddr16(c, d)] = (bf16_t)e;
      psum[r] += e;
    }
  }
#pragma unroll
  for (int m = 1; m < 16; m <<= 1)
#pragma unroll
    for (int r = 0; r < 4; ++r) psum[r] += __shfl_xor(psum[r], m);
  if (l16 == 0)
#pragma unroll
    for (int r = 0; r < 4; ++r) redsum[wave][quad * 4 + r] = psum[r];
  __syncthreads();
  if (tid < 16)
    rowrinv[tid] = 1.f / (redsum[0][tid] + redsum[1][tid] + redsum[2][tid] + redsum[3][tid]);
  __syncthreads();   // ebuf + rowrinv visible; tile-0 DMA also drained here

  // ---- Phase C: out = e @ vT. Barrier-free, explicit vmcnt pipeline. ----
  f32x4 oacc[4];
#pragma unroll
  for (int jn = 0; jn < 4; ++jn) oacc[jn] = (f32x4){0.f, 0.f, 0.f, 0.f};

  for (int ks = 0; ks < 32; ++ks) {
    const bf16_t* cur = myvs[ks & 1];
    // 1) issue next tile's DMA into the other buffer
    if (ks < 31) {
      bf16_t* nxt = myvs[(ks + 1) & 1];
      const int koff = (ks + 1) * 32;
#pragma unroll
      for (int t = 0; t < 4; ++t) {
        const int r = t * 16 + (lane >> 2);
        const int gg = ((lane & 3) - (r + (r >> 2))) & 3;
        const bf16_t* src = vb + (size_t)r * C_ + koff + gg * 8;
        __builtin_amdgcn_global_load_lds(
            (const __attribute__((address_space(1))) void*)src,
            (__attribute__((address_space(3))) void*)(nxt + t * 512 + lane * 8),
            16, 0, 0);
      }
      WAIT_VMCNT(4);   // tile ks's 4 DMAs (oldest) complete; next tile in flight
    } else {
      WAIT_VMCNT(0);
    }
    // 2) read current fragments from LDS and accumulate
    const int gch = ks * 4 + quad;
    const int ph  = (gch & ~7) | ((gch + l16) & 7);
    const bf16x8 ae = *(const bf16x8*)(ebuf + ((size_t)l16 << 10) + ph * 8);
    bf16x8 bv[4];
#pragma unroll
    for (int jn = 0; jn < 4; ++jn) {
      const int rl = jn * 16 + l16;
      const int s = (quad + rl + (rl >> 2)) & 3;
      bv[jn] = *(const bf16x8*)(cur + rl * 32 + s * 8);
    }
#pragma unroll
    for (int jn = 0; jn < 4; ++jn)
      oacc[jn] = mfma16(ae, bv[jn], oacc[jn]);
  }

  const float alpha = alphap[0];
#pragma unroll
  for (int jn = 0; jn < 4; ++jn)
#pragma unroll
    for (int r = 0; r < 4; ++r) {
      const int c = c0 + quad * 4 + r;
      const int n = wave * 64 + jn * 16 + l16;
      const size_t idx = ((size_t)b * C_ + c) * N_ + n;
      out[idx] = alpha * (oacc[jn][r] * rowrinv[quad * 4 + r]) + x[idx];
    }
}

extern "C" void kernel_launch(void* const* d_in, const int* in_sizes, int n_in,
                              void* d_out, int out_size, void* d_ws, size_t ws_size,
                              hipStream_t stream) {
  const float* x    = (const float*)d_in[0];
  const float* Wq   = (const float*)d_in[1];
  const float* Wk   = (const float*)d_in[2];
  const float* Wv   = (const float*)d_in[3];
  const float* bn1g = (const float*)d_in[4];
  const float* bn1b = (const float*)d_in[5];
  const float* bn1m = (const float*)d_in[6];
  const float* bn1v = (const float*)d_in[7];
  const float* bn2g = (const float*)d_in[8];
  const float* bn2b = (const float*)d_in[9];
  const float* bn2m = (const float*)d_in[10];
  const float* bn2v = (const float*)d_in[11];
  const float* bn3g = (const float*)d_in[12];
  const float* bn3b = (const float*)d_in[13];
  const float* bn3m = (const float*)d_in[14];
  const float* bn3v = (const float*)d_in[15];
  const float* alph = (const float*)d_in[16];
  float* outp = (float*)d_out;

  char* ws = (char*)d_ws;
  bf16_t* qt   = (bf16_t*)(ws);                              // 4 MiB  (B,C,DQ)
  bf16_t* kt   = (bf16_t*)(ws + (size_t)(4u << 20));         // 4 MiB  (B,C,DQ)
  bf16_t* vT   = (bf16_t*)(ws + (size_t)(8u << 20));         // 16 MiB (B,N,C)
  bf16_t* xT   = (bf16_t*)(ws + (size_t)(24u << 20));        // 16 MiB (B,N,C)
  bf16_t* Wvb  = (bf16_t*)(ws + (size_t)(40u << 20));        // 2 MiB  (C,C)
  bf16_t* Wqkb = (bf16_t*)(ws + (size_t)(42u << 20));        // 64 KiB (128,N)

  k_trans<<<dim3(8, 32, 32), dim3(32, 8, 1), 0, stream>>>(x, xT);
  k_cvt<<<dim3(528), 256, 0, stream>>>(Wv, Wq, Wk, Wvb, Wqkb);
  k_qk<<<dim3(16, 32), 256, 0, stream>>>(x, Wqkb,
                                         bn1g, bn1b, bn1m, bn1v,
                                         bn2g, bn2b, bn2m, bn2v, qt, kt);
  k_vgemm<<<dim3(8, 64), 256, 0, stream>>>(Wvb, xT, bn3g, bn3b, bn3m, bn3v, vT);
  k_fused<<<dim3(2048), 256, 0, stream>>>(qt, kt, vT, x, alph, outp);
}